// Round 1
// baseline (242.182 us; speedup 1.0000x reference)
//
#include <hip/hip_runtime.h>

constexpr int NT = 1024;
constexpr int ND = 512;
constexpr int NB = 6;
constexpr int NH = 196;
constexpr int KL = 128;

__global__ __launch_bounds__(256) void net_fused(
    const float* __restrict__ x0,
    const float* __restrict__ x,
    const float* __restrict__ Nn,
    const float* __restrict__ basis,
    const float* __restrict__ v,
    const float* __restrict__ W0,
    const float* __restrict__ b0,
    const float* __restrict__ W1,
    const float* __restrict__ b1,
    const float* __restrict__ W2,
    const float* __restrict__ b2,
    float* __restrict__ out)
{
    __shared__ float feat[ND][16];
    __shared__ float red[4][3];
    __shared__ float pool4[4][NH];
    __shared__ float pool_s[NH];
    __shared__ float h1_s[NH];

    const int r = blockIdx.x;          // b*NT + i
    const int t = threadIdx.x;
    const int wid = t >> 6;
    const int lane = t & 63;
    const int b = r >> 10;             // NT = 1024
    const size_t rowbase = (size_t)r * ND * 3;

    // ---------- phase 1: vbulk = mean_j v[r,j,:] ----------
    float s0 = 0.f, s1 = 0.f, s2 = 0.f;
    for (int j = t; j < ND; j += 256) {
        const float* vp = v + rowbase + 3 * j;
        s0 += vp[0]; s1 += vp[1]; s2 += vp[2];
    }
    #pragma unroll
    for (int off = 32; off > 0; off >>= 1) {
        s0 += __shfl_down(s0, off);
        s1 += __shfl_down(s1, off);
        s2 += __shfl_down(s2, off);
    }
    if (lane == 0) { red[wid][0] = s0; red[wid][1] = s1; red[wid][2] = s2; }
    __syncthreads();
    const float inv_nd = 1.0f / (float)ND;
    const float vb0 = (red[0][0] + red[1][0] + red[2][0] + red[3][0]) * inv_nd;
    const float vb1 = (red[0][1] + red[1][1] + red[2][1] + red[3][1]) * inv_nd;
    const float vb2 = (red[0][2] + red[1][2] + red[2][2] + red[3][2]) * inv_nd;

    // basis vectors (broadcast loads, L2-hot)
    float bx[NB], by[NB], bz[NB];
    {
        const float* bp = basis + (size_t)b * NB * 3;
        #pragma unroll
        for (int k = 0; k < NB; k++) { bx[k] = bp[3*k]; by[k] = bp[3*k+1]; bz[k] = bp[3*k+2]; }
    }

    // ---------- phase 2: per-j features -> LDS ----------
    for (int j = t; j < ND; j += 256) {
        const float* xp = x + rowbase + 3 * j;
        const float* vp = v + rowbase + 3 * j;
        float xa = xp[0], xbv = xp[1], xc = xp[2];
        float va = vp[0] - vb0, vbv = vp[1] - vb1, vcv = vp[2] - vb2;
        float xn = sqrtf(xa*xa + xbv*xbv + xc*xc);
        float vn = sqrtf(va*va + vbv*vbv + vcv*vcv);
        float rx = 1.0f / xn, rv = 1.0f / vn;
        float f[16];
        f[0] = xn;
        #pragma unroll
        for (int k = 0; k < NB; k++) f[1+k] = (xa*bx[k] + xbv*by[k] + xc*bz[k]) * rx;
        f[7] = vn;
        #pragma unroll
        for (int k = 0; k < NB; k++) f[8+k] = (va*bx[k] + vbv*by[k] + vcv*bz[k]) * rv;
        f[14] = 0.f; f[15] = 0.f;
        #pragma unroll
        for (int q2 = 0; q2 < 4; q2++)
            *reinterpret_cast<float4*>(&feat[j][4*q2]) =
                make_float4(f[4*q2], f[4*q2+1], f[4*q2+2], f[4*q2+3]);
    }

    // ---------- constant features (redundant per-thread, cheap) ----------
    float cf[15];
    {
        const float* xp = x0 + (size_t)r * 3;
        float a0 = xp[0], a1 = xp[1], a2 = xp[2];
        float x0n = sqrtf(a0*a0 + a1*a1 + a2*a2);
        float vbn = sqrtf(vb0*vb0 + vb1*vb1 + vb2*vb2);
        float r0 = 1.0f / x0n, r1 = 1.0f / vbn;
        cf[0] = Nn[r];
        cf[1] = x0n;
        #pragma unroll
        for (int k = 0; k < NB; k++) cf[2+k] = (a0*bx[k] + a1*by[k] + a2*bz[k]) * r0;
        cf[8] = vbn;
        #pragma unroll
        for (int k = 0; k < NB; k++) cf[9+k] = (vb0*bx[k] + vb1*by[k] + vb2*bz[k]) * r1;
    }

    // per-lane channel groups: c = lane + 64*q, q = 0..3 (c < 196 active)
    float wq[4][14];
    float consth[4];
    float acc[4] = {0.f, 0.f, 0.f, 0.f};
    #pragma unroll
    for (int q = 0; q < 4; q++) {
        int c = lane + 64 * q;
        bool act = (c < NH);
        float ch = act ? b0[c] : 0.f;
        #pragma unroll
        for (int f2 = 0; f2 < 15; f2++) ch += cf[f2] * (act ? W0[f2*NH + c] : 0.f);
        consth[q] = ch;
        #pragma unroll
        for (int f2 = 0; f2 < 14; f2++) wq[q][f2] = act ? W0[(15+f2)*NH + c] : 0.f;
    }
    __syncthreads();

    // ---------- phase 3: per-j matvec + lrelu + pool (wave owns 128 j) ----------
    const int jbase = wid << 7;
    #pragma unroll 2
    for (int jj = 0; jj < 128; jj++) {
        int j = jbase + jj;
        const float4 q0 = *reinterpret_cast<const float4*>(&feat[j][0]);
        const float4 q1 = *reinterpret_cast<const float4*>(&feat[j][4]);
        const float4 q2 = *reinterpret_cast<const float4*>(&feat[j][8]);
        const float2 q3 = *reinterpret_cast<const float2*>(&feat[j][12]);
        const float fv[14] = {q0.x, q0.y, q0.z, q0.w, q1.x, q1.y, q1.z, q1.w,
                              q2.x, q2.y, q2.z, q2.w, q3.x, q3.y};
        #pragma unroll
        for (int q = 0; q < 4; q++) {
            float h = consth[q];
            #pragma unroll
            for (int f2 = 0; f2 < 14; f2++) h += fv[f2] * wq[q][f2];
            acc[q] += (h > 0.f) ? h : 0.01f * h;
        }
    }
    #pragma unroll
    for (int q = 0; q < 4; q++) {
        int c = lane + 64 * q;
        if (c < NH) pool4[wid][c] = acc[q];
    }
    __syncthreads();

    // ---------- pool combine ----------
    if (t < NH) {
        float p = (pool4[0][t] + pool4[1][t] + pool4[2][t] + pool4[3][t]) * inv_nd;
        pool_s[t] = p;
    }
    __syncthreads();

    // ---------- phase 4: h1 = lrelu(pool @ W1 + b1) ----------
    if (t < NH) {
        float h = b1[t];
        #pragma unroll 4
        for (int k = 0; k < NH; k++) h += pool_s[k] * W1[(size_t)k * NH + t];
        h = (h > 0.f) ? h : 0.01f * h;
        h1_s[t] = h;
    }
    __syncthreads();

    // ---------- phase 5: out = h1 @ W2 + b2 ----------
    if (t < KL) {
        float o = b2[t];
        #pragma unroll 4
        for (int k = 0; k < NH; k++) o += h1_s[k] * W2[(size_t)k * KL + t];
        out[(size_t)r * KL + t] = o;
    }
}

extern "C" void kernel_launch(void* const* d_in, const int* in_sizes, int n_in,
                              void* d_out, int out_size, void* d_ws, size_t ws_size,
                              hipStream_t stream) {
    const float* x0    = (const float*)d_in[0];
    const float* x     = (const float*)d_in[1];
    const float* Nn    = (const float*)d_in[2];
    const float* basis = (const float*)d_in[3];
    const float* v     = (const float*)d_in[4];
    const float* W0    = (const float*)d_in[5];
    const float* b0    = (const float*)d_in[6];
    const float* W1    = (const float*)d_in[7];
    const float* b1    = (const float*)d_in[8];
    const float* W2    = (const float*)d_in[9];
    const float* b2    = (const float*)d_in[10];
    float* out = (float*)d_out;

    const int rows = in_sizes[2];   // B * NT = 2048
    net_fused<<<dim3(rows), dim3(256), 0, stream>>>(
        x0, x, Nn, basis, v, W0, b0, W1, b1, W2, b2, out);
}

// Round 5
// 171.374 us; speedup vs baseline: 1.4132x; 1.4132x over previous
//
#include <hip/hip_runtime.h>

typedef __bf16 bf16x8 __attribute__((ext_vector_type(8)));
typedef float f32x16 __attribute__((ext_vector_type(16)));

constexpr int NT = 1024;
constexpr int ND = 512;
constexpr int NB = 6;
constexpr int NH = 196;
constexpr int KL = 128;
constexpr int NHP = 224;   // 7 * 32 padded channels

__device__ __forceinline__ unsigned short f2bf(float f) {
    unsigned int b = __float_as_uint(f);
    b += 0x7FFFu + ((b >> 16) & 1u);
    return (unsigned short)(b >> 16);
}

// ---------------- kernel A: features + layer0 MFMA + lrelu + pool ----------------
__global__ __launch_bounds__(256) void pool_kernel(
    const float* __restrict__ x0, const float* __restrict__ x,
    const float* __restrict__ Nn, const float* __restrict__ basis,
    const float* __restrict__ v,  const float* __restrict__ W0,
    const float* __restrict__ b0, float* __restrict__ pool_out)
{
    __shared__ __align__(16) unsigned short featB[ND][16]; // bf16 per-j features, 32B/row
    __shared__ float consthL[NHP];
    __shared__ float pool4[4][NHP];
    __shared__ float red[4][3];

    const int r = blockIdx.x;          // b*NT + i
    const int t = threadIdx.x;
    const int wid = t >> 6;
    const int lane = t & 63;
    const int b = r >> 10;             // NT = 1024
    const size_t rowbase = (size_t)r * ND * 3;

    // ---- vbulk = mean_j v ----
    float s0 = 0.f, s1 = 0.f, s2 = 0.f;
    for (int j = t; j < ND; j += 256) {
        const float* vp = v + rowbase + 3 * j;
        s0 += vp[0]; s1 += vp[1]; s2 += vp[2];
    }
    #pragma unroll
    for (int off = 32; off > 0; off >>= 1) {
        s0 += __shfl_down(s0, off);
        s1 += __shfl_down(s1, off);
        s2 += __shfl_down(s2, off);
    }
    if (lane == 0) { red[wid][0] = s0; red[wid][1] = s1; red[wid][2] = s2; }
    __syncthreads();
    const float inv_nd = 1.0f / (float)ND;
    const float vb0 = (red[0][0] + red[1][0] + red[2][0] + red[3][0]) * inv_nd;
    const float vb1 = (red[0][1] + red[1][1] + red[2][1] + red[3][1]) * inv_nd;
    const float vb2 = (red[0][2] + red[1][2] + red[2][2] + red[3][2]) * inv_nd;

    // basis (L2-hot broadcast)
    float bx[NB], by[NB], bz[NB];
    {
        const float* bp = basis + (size_t)b * NB * 3;
        #pragma unroll
        for (int k = 0; k < NB; k++) { bx[k] = bp[3*k]; by[k] = bp[3*k+1]; bz[k] = bp[3*k+2]; }
    }

    // ---- per-j features -> LDS (bf16) ----
    for (int j = t; j < ND; j += 256) {
        const float* xp = x + rowbase + 3 * j;
        const float* vp = v + rowbase + 3 * j;
        float xa = xp[0], xbv = xp[1], xc = xp[2];
        float va = vp[0] - vb0, vbv = vp[1] - vb1, vcv = vp[2] - vb2;
        float xn = sqrtf(xa*xa + xbv*xbv + xc*xc);
        float vn = sqrtf(va*va + vbv*vbv + vcv*vcv);
        float rx = 1.0f / xn, rv = 1.0f / vn;
        float f[14];
        f[0] = xn;
        #pragma unroll
        for (int k = 0; k < NB; k++) f[1+k] = (xa*bx[k] + xbv*by[k] + xc*bz[k]) * rx;
        f[7] = vn;
        #pragma unroll
        for (int k = 0; k < NB; k++) f[8+k] = (va*bx[k] + vbv*by[k] + vcv*bz[k]) * rv;
        unsigned int w[8];
        #pragma unroll
        for (int q = 0; q < 7; q++)
            w[q] = (unsigned int)f2bf(f[2*q]) | ((unsigned int)f2bf(f[2*q+1]) << 16);
        w[7] = 0u;   // k = 14,15 zero pad
        *reinterpret_cast<uint4*>(&featB[j][0]) = make_uint4(w[0], w[1], w[2], w[3]);
        *reinterpret_cast<uint4*>(&featB[j][8]) = make_uint4(w[4], w[5], w[6], w[7]);
    }

    // ---- constant features (fp32, per-channel bias-fold) ----
    float cf[15];
    {
        const float* xp = x0 + (size_t)r * 3;
        float a0 = xp[0], a1 = xp[1], a2 = xp[2];
        float x0n = sqrtf(a0*a0 + a1*a1 + a2*a2);
        float vbn = sqrtf(vb0*vb0 + vb1*vb1 + vb2*vb2);
        float r0 = 1.0f / x0n, r1 = 1.0f / vbn;
        cf[0] = Nn[r];
        cf[1] = x0n;
        #pragma unroll
        for (int k = 0; k < NB; k++) cf[2+k] = (a0*bx[k] + a1*by[k] + a2*bz[k]) * r0;
        cf[8] = vbn;
        #pragma unroll
        for (int k = 0; k < NB; k++) cf[9+k] = (vb0*bx[k] + vb1*by[k] + vb2*bz[k]) * r1;
    }
    if (t < NHP) {
        float ch = 0.f;
        if (t < NH) {
            ch = b0[t];
            #pragma unroll
            for (int f2 = 0; f2 < 15; f2++) ch += cf[f2] * W0[f2 * NH + t];
        }
        consthL[t] = ch;
    }

    // ---- B fragments: W0 per-j rows (15..28) as bf16, K padded to 16 ----
    // layout: lane holds col = lane&31, k = 8*(lane>>5) + e
    const int col = lane & 31;
    const int khalf = lane >> 5;
    bf16x8 bfr[7];
    #pragma unroll
    for (int nt = 0; nt < 7; nt++) {
        int c = nt * 32 + col;
        #pragma unroll
        for (int e = 0; e < 8; e++) {
            int k = khalf * 8 + e;
            float wv = (c < NH && k < 14) ? W0[(15 + k) * NH + c] : 0.f;
            bfr[nt][e] = (__bf16)wv;
        }
    }
    __syncthreads();

    float ch[7];
    #pragma unroll
    for (int nt = 0; nt < 7; nt++) ch[nt] = consthL[nt * 32 + col];

    // ---- MFMA: per M-tile (32 j) x 7 N-tiles, acc init = const part ----
    float poolw[7] = {0.f,0.f,0.f,0.f,0.f,0.f,0.f};
    #pragma unroll
    for (int mi = 0; mi < 4; mi++) {
        const int row = (wid * 4 + mi) * 32 + col;   // A row = lane&31 within tile
        uint4 araw = *reinterpret_cast<const uint4*>(&featB[row][khalf * 8]);
        bf16x8 afrag = __builtin_bit_cast(bf16x8, araw);
        #pragma unroll
        for (int nt = 0; nt < 7; nt++) {
            f32x16 acc;
            #pragma unroll
            for (int i = 0; i < 16; i++) acc[i] = ch[nt];
            acc = __builtin_amdgcn_mfma_f32_32x32x16_bf16(afrag, bfr[nt], acc, 0, 0, 0);
            float s = 0.f;
            #pragma unroll
            for (int i = 0; i < 16; i++) { float h = acc[i]; s += fmaxf(h, 0.01f * h); }
            poolw[nt] += s;
        }
    }
    #pragma unroll
    for (int nt = 0; nt < 7; nt++) poolw[nt] += __shfl_xor(poolw[nt], 32);
    if (lane < 32) {
        #pragma unroll
        for (int nt = 0; nt < 7; nt++) pool4[wid][nt * 32 + lane] = poolw[nt];
    }
    __syncthreads();

    if (t < NH) {
        float p = (pool4[0][t] + pool4[1][t] + pool4[2][t] + pool4[3][t]) * inv_nd;
        pool_out[(size_t)r * NH + t] = p;
    }
}

// ---------------- kernel B: h1 = lrelu(pool@W1+b1); out = h1@W2+b2 ----------------
__global__ __launch_bounds__(256) void head_kernel(
    const float* __restrict__ pool, const float* __restrict__ W1,
    const float* __restrict__ b1,   const float* __restrict__ W2,
    const float* __restrict__ b2,   float* __restrict__ out)
{
    __shared__ float poolL[4][200];
    __shared__ float h1L[4][200];
    const int t = threadIdx.x;
    const int wid = t >> 6;      // row within block
    const int lane = t & 63;
    const int r0 = blockIdx.x * 4;

    if (t < NH) {
        #pragma unroll
        for (int rr = 0; rr < 4; rr++) poolL[rr][t] = pool[(size_t)(r0 + rr) * NH + t];
    }
    __syncthreads();

    // stage 1: h1[wid][c], c = lane + {0,64,128,192}
    {
        const int c0 = lane, c1 = lane + 64, c2 = lane + 128, c3 = lane + 192;
        const int c3m = (c3 < NH) ? c3 : 0;
        float h0 = b1[c0], h1 = b1[c1], h2 = b1[c2], h3 = b1[c3m];
        #pragma unroll 4
        for (int kk = 0; kk < NH; kk++) {
            float p = poolL[wid][kk];
            const float* wrow = W1 + (size_t)kk * NH;
            h0 += p * wrow[c0];
            h1 += p * wrow[c1];
            h2 += p * wrow[c2];
            h3 += p * wrow[c3m];
        }
        h1L[wid][c0] = fmaxf(h0, 0.01f * h0);
        h1L[wid][c1] = fmaxf(h1, 0.01f * h1);
        h1L[wid][c2] = fmaxf(h2, 0.01f * h2);
        if (c3 < NH) h1L[wid][c3] = fmaxf(h3, 0.01f * h3);
    }
    __syncthreads();

    // stage 2: out[wid][c], c = lane + {0,64}
    {
        const int c0 = lane, c1 = lane + 64;
        float o0 = b2[c0], o1 = b2[c1];
        #pragma unroll 4
        for (int kk = 0; kk < NH; kk++) {
            float h = h1L[wid][kk];
            const float* wrow = W2 + (size_t)kk * KL;
            o0 += h * wrow[c0];
            o1 += h * wrow[c1];
        }
        out[(size_t)(r0 + wid) * KL + c0] = o0;
        out[(size_t)(r0 + wid) * KL + c1] = o1;
    }
}

extern "C" void kernel_launch(void* const* d_in, const int* in_sizes, int n_in,
                              void* d_out, int out_size, void* d_ws, size_t ws_size,
                              hipStream_t stream) {
    const float* x0    = (const float*)d_in[0];
    const float* x     = (const float*)d_in[1];
    const float* Nn    = (const float*)d_in[2];
    const float* basis = (const float*)d_in[3];
    const float* v     = (const float*)d_in[4];
    const float* W0    = (const float*)d_in[5];
    const float* b0    = (const float*)d_in[6];
    const float* W1    = (const float*)d_in[7];
    const float* b1    = (const float*)d_in[8];
    const float* W2    = (const float*)d_in[9];
    const float* b2    = (const float*)d_in[10];
    float* out = (float*)d_out;
    float* pool_ws = (float*)d_ws;      // 2048 * 196 * 4 B = 1.6 MB

    const int rows = in_sizes[2];       // B * NT = 2048
    pool_kernel<<<dim3(rows), dim3(256), 0, stream>>>(
        x0, x, Nn, basis, v, W0, b0, pool_ws);
    head_kernel<<<dim3(rows / 4), dim3(256), 0, stream>>>(
        pool_ws, W1, b1, W2, b2, out);
}

// Round 9
// 165.196 us; speedup vs baseline: 1.4660x; 1.0374x over previous
//
#include <hip/hip_runtime.h>

typedef __bf16 bf16x8 __attribute__((ext_vector_type(8)));
typedef float f32x16 __attribute__((ext_vector_type(16)));

constexpr int NT = 1024;
constexpr int ND = 512;
constexpr int NB = 6;
constexpr int NH = 196;
constexpr int KL = 128;
constexpr int NHP = 224;   // 7 * 32 padded channels

__device__ __forceinline__ unsigned short f2bf(float f) {
    unsigned int b = __float_as_uint(f);
    b += 0x7FFFu + ((b >> 16) & 1u);
    return (unsigned short)(b >> 16);
}

// ---------- prep: pack W0 per-j rows (15..28) into MFMA B-fragments (bf16) ----------
// layout: frag[nt*64 + lane] = uint4 of 8 bf16, lane holds col=lane&31, k=8*(lane>>5)+e
__global__ __launch_bounds__(448) void prep_kernel(const float* __restrict__ W0,
                                                   uint4* __restrict__ frag)
{
    const int tid = threadIdx.x;          // 448 = 7 nt * 64 lanes
    const int l = tid & 63;
    const int nt = tid >> 6;
    const int col = l & 31;
    const int khalf = l >> 5;
    const int c = nt * 32 + col;
    unsigned int w[4];
    #pragma unroll
    for (int d = 0; d < 4; d++) {
        int k0 = khalf * 8 + 2 * d;
        int k1 = k0 + 1;
        float v0 = (c < NH && k0 < 14) ? W0[(15 + k0) * NH + c] : 0.f;
        float v1 = (c < NH && k1 < 14) ? W0[(15 + k1) * NH + c] : 0.f;
        w[d] = (unsigned int)f2bf(v0) | ((unsigned int)f2bf(v1) << 16);
    }
    frag[tid] = make_uint4(w[0], w[1], w[2], w[3]);
}

// ---------- fused: features + layer0 MFMA + lrelu + pool + W1 + W2 ----------
__global__ __launch_bounds__(256) void fused_kernel(
    const float* __restrict__ x0, const float* __restrict__ x,
    const float* __restrict__ Nn, const float* __restrict__ basis,
    const float* __restrict__ v,  const float* __restrict__ W0,
    const float* __restrict__ b0, const float* __restrict__ W1,
    const float* __restrict__ b1, const float* __restrict__ W2,
    const float* __restrict__ b2, const uint4* __restrict__ w0frag,
    float* __restrict__ out)
{
    __shared__ __align__(16) unsigned short featB[ND][16]; // bf16 features, 32B/row
    __shared__ float consthL[NHP];
    __shared__ float pool4[4][NHP];
    __shared__ float red[4][3];
    __shared__ __align__(16) float pool_s[NH];
    __shared__ __align__(16) float h1_s[NH];

    const int r = blockIdx.x;          // b*NT + i
    const int t = threadIdx.x;
    const int wid = t >> 6;
    const int lane = t & 63;
    const int b = r >> 10;             // NT = 1024
    const size_t rowbase = (size_t)r * ND * 3;

    // ---- vbulk = mean_j v ----
    float s0 = 0.f, s1 = 0.f, s2 = 0.f;
    for (int j = t; j < ND; j += 256) {
        const float* vp = v + rowbase + 3 * j;
        s0 += vp[0]; s1 += vp[1]; s2 += vp[2];
    }
    #pragma unroll
    for (int off = 32; off > 0; off >>= 1) {
        s0 += __shfl_down(s0, off);
        s1 += __shfl_down(s1, off);
        s2 += __shfl_down(s2, off);
    }
    if (lane == 0) { red[wid][0] = s0; red[wid][1] = s1; red[wid][2] = s2; }
    __syncthreads();
    const float inv_nd = 1.0f / (float)ND;
    const float vb0 = (red[0][0] + red[1][0] + red[2][0] + red[3][0]) * inv_nd;
    const float vb1 = (red[0][1] + red[1][1] + red[2][1] + red[3][1]) * inv_nd;
    const float vb2 = (red[0][2] + red[1][2] + red[2][2] + red[3][2]) * inv_nd;

    // basis (L2-hot broadcast)
    float bx[NB], by[NB], bz[NB];
    {
        const float* bp = basis + (size_t)b * NB * 3;
        #pragma unroll
        for (int k = 0; k < NB; k++) { bx[k] = bp[3*k]; by[k] = bp[3*k+1]; bz[k] = bp[3*k+2]; }
    }

    // ---- per-j features -> LDS (bf16) ----
    for (int j = t; j < ND; j += 256) {
        const float* xp = x + rowbase + 3 * j;
        const float* vp = v + rowbase + 3 * j;
        float xa = xp[0], xbv = xp[1], xc = xp[2];
        float va = vp[0] - vb0, vbv = vp[1] - vb1, vcv = vp[2] - vb2;
        float n2x = xa*xa + xbv*xbv + xc*xc;
        float n2v = va*va + vbv*vbv + vcv*vcv;
        float rx = __frsqrt_rn(n2x);
        float rv = __frsqrt_rn(n2v);
        float f[14];
        f[0] = n2x * rx;                       // |x|
        #pragma unroll
        for (int k = 0; k < NB; k++) f[1+k] = (xa*bx[k] + xbv*by[k] + xc*bz[k]) * rx;
        f[7] = n2v * rv;                       // |vc|
        #pragma unroll
        for (int k = 0; k < NB; k++) f[8+k] = (va*bx[k] + vbv*by[k] + vcv*bz[k]) * rv;
        bf16x8 lo, hi;
        #pragma unroll
        for (int e = 0; e < 8; e++) lo[e] = (__bf16)f[e];
        #pragma unroll
        for (int e = 0; e < 6; e++) hi[e] = (__bf16)f[8+e];
        hi[6] = (__bf16)0.f; hi[7] = (__bf16)0.f;   // k = 14,15 zero pad
        *reinterpret_cast<uint4*>(&featB[j][0]) = __builtin_bit_cast(uint4, lo);
        *reinterpret_cast<uint4*>(&featB[j][8]) = __builtin_bit_cast(uint4, hi);
    }

    // ---- B fragments: pre-packed by prep_kernel, coalesced dwordx4 ----
    bf16x8 bfr[7];
    #pragma unroll
    for (int nt = 0; nt < 7; nt++)
        bfr[nt] = __builtin_bit_cast(bf16x8, w0frag[nt * 64 + lane]);

    // ---- constant features (fp32, folded into acc init) ----
    float cf[15];
    {
        const float* xp = x0 + (size_t)r * 3;
        float a0 = xp[0], a1 = xp[1], a2 = xp[2];
        float n20 = a0*a0 + a1*a1 + a2*a2;
        float n2b = vb0*vb0 + vb1*vb1 + vb2*vb2;
        float r0 = __frsqrt_rn(n20);
        float r1 = __frsqrt_rn(n2b);
        cf[0] = Nn[r];
        cf[1] = n20 * r0;
        #pragma unroll
        for (int k = 0; k < NB; k++) cf[2+k] = (a0*bx[k] + a1*by[k] + a2*bz[k]) * r0;
        cf[8] = n2b * r1;
        #pragma unroll
        for (int k = 0; k < NB; k++) cf[9+k] = (vb0*bx[k] + vb1*by[k] + vb2*bz[k]) * r1;
    }
    if (t < NHP) {
        float ch = 0.f;
        if (t < NH) {
            ch = b0[t];
            #pragma unroll
            for (int f2 = 0; f2 < 15; f2++) ch += cf[f2] * W0[f2 * NH + t];
        }
        consthL[t] = ch;
    }
    __syncthreads();

    const int col = lane & 31;
    const int khalf = lane >> 5;
    float ch[7];
    #pragma unroll
    for (int nt = 0; nt < 7; nt++) ch[nt] = consthL[nt * 32 + col];

    // ---- MFMA: 4 M-tiles (32 j each) x 7 N-tiles, acc init = const part ----
    float poolw[7] = {0.f,0.f,0.f,0.f,0.f,0.f,0.f};
    #pragma unroll
    for (int mi = 0; mi < 4; mi++) {
        const int row = (wid * 4 + mi) * 32 + col;
        uint4 araw = *reinterpret_cast<const uint4*>(&featB[row][khalf * 8]);
        bf16x8 afrag = __builtin_bit_cast(bf16x8, araw);
        #pragma unroll
        for (int nt = 0; nt < 7; nt++) {
            f32x16 acc;
            #pragma unroll
            for (int i = 0; i < 16; i++) acc[i] = ch[nt];
            acc = __builtin_amdgcn_mfma_f32_32x32x16_bf16(afrag, bfr[nt], acc, 0, 0, 0);
            float s = 0.f;
            #pragma unroll
            for (int i = 0; i < 16; i++) { float h = acc[i]; s += fmaxf(h, 0.01f * h); }
            poolw[nt] += s;
        }
    }
    #pragma unroll
    for (int nt = 0; nt < 7; nt++) poolw[nt] += __shfl_xor(poolw[nt], 32);
    if (lane < 32) {
        #pragma unroll
        for (int nt = 0; nt < 7; nt++) pool4[wid][nt * 32 + lane] = poolw[nt];
    }
    __syncthreads();

    // ---- pool combine ----
    if (t < NH)
        pool_s[t] = (pool4[0][t] + pool4[1][t] + pool4[2][t] + pool4[3][t]) * inv_nd;
    __syncthreads();

    // ---- head stage 1: h1 = lrelu(pool @ W1 + b1) ----
    if (t < NH) {
        float h = b1[t];
        const float* wcol = W1 + t;
        #pragma unroll 4
        for (int k = 0; k < NH; k += 4) {
            float4 p4 = *reinterpret_cast<const float4*>(&pool_s[k]);
            h += p4.x * wcol[(size_t)(k + 0) * NH];
            h += p4.y * wcol[(size_t)(k + 1) * NH];
            h += p4.z * wcol[(size_t)(k + 2) * NH];
            h += p4.w * wcol[(size_t)(k + 3) * NH];
        }
        h1_s[t] = fmaxf(h, 0.01f * h);
    }
    __syncthreads();

    // ---- head stage 2: out = h1 @ W2 + b2 ----
    if (t < KL) {
        float o = b2[t];
        const float* wcol = W2 + t;
        #pragma unroll 4
        for (int k = 0; k < NH; k += 4) {
            float4 h4 = *reinterpret_cast<const float4*>(&h1_s[k]);
            o += h4.x * wcol[(size_t)(k + 0) * KL];
            o += h4.y * wcol[(size_t)(k + 1) * KL];
            o += h4.z * wcol[(size_t)(k + 2) * KL];
            o += h4.w * wcol[(size_t)(k + 3) * KL];
        }
        out[(size_t)r * KL + t] = o;
    }
}

extern "C" void kernel_launch(void* const* d_in, const int* in_sizes, int n_in,
                              void* d_out, int out_size, void* d_ws, size_t ws_size,
                              hipStream_t stream) {
    const float* x0    = (const float*)d_in[0];
    const float* x     = (const float*)d_in[1];
    const float* Nn    = (const float*)d_in[2];
    const float* basis = (const float*)d_in[3];
    const float* v     = (const float*)d_in[4];
    const float* W0    = (const float*)d_in[5];
    const float* b0    = (const float*)d_in[6];
    const float* W1    = (const float*)d_in[7];
    const float* b1    = (const float*)d_in[8];
    const float* W2    = (const float*)d_in[9];
    const float* b2    = (const float*)d_in[10];
    float* out = (float*)d_out;
    uint4* w0frag = (uint4*)d_ws;       // 448 * 16 B = 7168 B

    const int rows = in_sizes[2];       // B * NT = 2048
    prep_kernel<<<dim3(1), dim3(448), 0, stream>>>(W0, w0frag);
    fused_kernel<<<dim3(rows), dim3(256), 0, stream>>>(
        x0, x, Nn, basis, v, W0, b0, W1, b1, W2, b2, w0frag, out);
}

// Round 11
// 151.361 us; speedup vs baseline: 1.6000x; 1.0914x over previous
//
#include <hip/hip_runtime.h>

typedef __bf16 bf16x8 __attribute__((ext_vector_type(8)));
typedef float f32x16 __attribute__((ext_vector_type(16)));

constexpr int NT = 1024;
constexpr int ND = 512;
constexpr int NB = 6;
constexpr int NH = 196;
constexpr int KL = 128;
constexpr int NHP = 224;   // 7 * 32 padded channels

__device__ __forceinline__ unsigned short f2bf(float f) {
    unsigned int b = __float_as_uint(f);
    b += 0x7FFFu + ((b >> 16) & 1u);
    return (unsigned short)(b >> 16);
}

// ---------- prep: pack W0 per-j rows (15..28) into MFMA B-fragments (bf16) ----------
// layout: frag[nt*64 + lane] = uint4 of 8 bf16, lane holds col=lane&31, k=8*(lane>>5)+e
__global__ __launch_bounds__(448) void prep_kernel(const float* __restrict__ W0,
                                                   uint4* __restrict__ frag)
{
    const int tid = threadIdx.x;          // 448 = 7 nt * 64 lanes
    const int l = tid & 63;
    const int nt = tid >> 6;
    const int col = l & 31;
    const int khalf = l >> 5;
    const int c = nt * 32 + col;
    unsigned int w[4];
    #pragma unroll
    for (int d = 0; d < 4; d++) {
        int k0 = khalf * 8 + 2 * d;
        int k1 = k0 + 1;
        float v0 = (c < NH && k0 < 14) ? W0[(15 + k0) * NH + c] : 0.f;
        float v1 = (c < NH && k1 < 14) ? W0[(15 + k1) * NH + c] : 0.f;
        w[d] = (unsigned int)f2bf(v0) | ((unsigned int)f2bf(v1) << 16);
    }
    frag[tid] = make_uint4(w[0], w[1], w[2], w[3]);
}

// ---------- pool: features + layer0 MFMA + lrelu-pool (A/B decomposition) ----------
__global__ __launch_bounds__(256) void pool_kernel(
    const float* __restrict__ x0, const float* __restrict__ x,
    const float* __restrict__ Nn, const float* __restrict__ basis,
    const float* __restrict__ v,  const float* __restrict__ W0,
    const float* __restrict__ b0, const uint4* __restrict__ w0frag,
    float* __restrict__ pool_out)
{
    __shared__ __align__(16) unsigned short featB[ND][16]; // bf16 features, 32B/row
    __shared__ float consthL[NHP];
    __shared__ float pool4A[4][NHP];
    __shared__ float pool4B[4][NHP];
    __shared__ float red[4][3];

    const int r = blockIdx.x;          // b*NT + i
    const int t = threadIdx.x;
    const int wid = t >> 6;
    const int lane = t & 63;
    const int b = r >> 10;             // NT = 1024
    const size_t rowbase = (size_t)r * ND * 3;

    // ---- vbulk = mean_j v ----
    float s0 = 0.f, s1 = 0.f, s2 = 0.f;
    for (int j = t; j < ND; j += 256) {
        const float* vp = v + rowbase + 3 * j;
        s0 += vp[0]; s1 += vp[1]; s2 += vp[2];
    }
    #pragma unroll
    for (int off = 32; off > 0; off >>= 1) {
        s0 += __shfl_down(s0, off);
        s1 += __shfl_down(s1, off);
        s2 += __shfl_down(s2, off);
    }
    if (lane == 0) { red[wid][0] = s0; red[wid][1] = s1; red[wid][2] = s2; }
    __syncthreads();
    const float inv_nd = 1.0f / (float)ND;
    const float vb0 = (red[0][0] + red[1][0] + red[2][0] + red[3][0]) * inv_nd;
    const float vb1 = (red[0][1] + red[1][1] + red[2][1] + red[3][1]) * inv_nd;
    const float vb2 = (red[0][2] + red[1][2] + red[2][2] + red[3][2]) * inv_nd;

    // basis (L2-hot broadcast)
    float bx[NB], by[NB], bz[NB];
    {
        const float* bp = basis + (size_t)b * NB * 3;
        #pragma unroll
        for (int k = 0; k < NB; k++) { bx[k] = bp[3*k]; by[k] = bp[3*k+1]; bz[k] = bp[3*k+2]; }
    }

    // ---- per-j features -> LDS (bf16) ----
    for (int j = t; j < ND; j += 256) {
        const float* xp = x + rowbase + 3 * j;
        const float* vp = v + rowbase + 3 * j;
        float xa = xp[0], xbv = xp[1], xc = xp[2];
        float va = vp[0] - vb0, vbv = vp[1] - vb1, vcv = vp[2] - vb2;
        float n2x = xa*xa + xbv*xbv + xc*xc;
        float n2v = va*va + vbv*vbv + vcv*vcv;
        float rx = __frsqrt_rn(n2x);
        float rv = __frsqrt_rn(n2v);
        float f[14];
        f[0] = n2x * rx;                       // |x|
        #pragma unroll
        for (int k = 0; k < NB; k++) f[1+k] = (xa*bx[k] + xbv*by[k] + xc*bz[k]) * rx;
        f[7] = n2v * rv;                       // |vc|
        #pragma unroll
        for (int k = 0; k < NB; k++) f[8+k] = (va*bx[k] + vbv*by[k] + vcv*bz[k]) * rv;
        bf16x8 lo, hi;
        #pragma unroll
        for (int e = 0; e < 8; e++) lo[e] = (__bf16)f[e];
        #pragma unroll
        for (int e = 0; e < 6; e++) hi[e] = (__bf16)f[8+e];
        hi[6] = (__bf16)0.f; hi[7] = (__bf16)0.f;   // k = 14,15 zero pad
        *reinterpret_cast<uint4*>(&featB[j][0]) = __builtin_bit_cast(uint4, lo);
        *reinterpret_cast<uint4*>(&featB[j][8]) = __builtin_bit_cast(uint4, hi);
    }

    // ---- B fragments: pre-packed, coalesced dwordx4 ----
    bf16x8 bfr[7];
    #pragma unroll
    for (int nt = 0; nt < 7; nt++)
        bfr[nt] = __builtin_bit_cast(bf16x8, w0frag[nt * 64 + lane]);

    // ---- constant features (fp32, folded into acc init) ----
    float cf[15];
    {
        const float* xp = x0 + (size_t)r * 3;
        float a0 = xp[0], a1 = xp[1], a2 = xp[2];
        float n20 = a0*a0 + a1*a1 + a2*a2;
        float n2b = vb0*vb0 + vb1*vb1 + vb2*vb2;
        float r0 = __frsqrt_rn(n20);
        float r1 = __frsqrt_rn(n2b);
        cf[0] = Nn[r];
        cf[1] = n20 * r0;
        #pragma unroll
        for (int k = 0; k < NB; k++) cf[2+k] = (a0*bx[k] + a1*by[k] + a2*bz[k]) * r0;
        cf[8] = n2b * r1;
        #pragma unroll
        for (int k = 0; k < NB; k++) cf[9+k] = (vb0*bx[k] + vb1*by[k] + vb2*bz[k]) * r1;
    }
    if (t < NHP) {
        float ch = 0.f;
        if (t < NH) {
            ch = b0[t];
            #pragma unroll
            for (int f2 = 0; f2 < 15; f2++) ch += cf[f2] * W0[f2 * NH + t];
        }
        consthL[t] = ch;
    }
    __syncthreads();

    const int col = lane & 31;
    const int khalf = lane >> 5;
    float ch[7];
    #pragma unroll
    for (int nt = 0; nt < 7; nt++) ch[nt] = consthL[nt * 32 + col];

    // ---- MFMA + A/B pooling: lrelu(h) = 0.505h + 0.495|h| (|h| is a free mod) ----
    float pA[7] = {0.f,0.f,0.f,0.f,0.f,0.f,0.f};
    float pB[7] = {0.f,0.f,0.f,0.f,0.f,0.f,0.f};
    #pragma unroll
    for (int mi = 0; mi < 4; mi++) {
        const int row = (wid * 4 + mi) * 32 + col;
        uint4 araw = *reinterpret_cast<const uint4*>(&featB[row][khalf * 8]);
        bf16x8 afrag = __builtin_bit_cast(bf16x8, araw);
        #pragma unroll
        for (int nt = 0; nt < 7; nt++) {
            f32x16 acc;
            #pragma unroll
            for (int i = 0; i < 16; i++) acc[i] = ch[nt];
            acc = __builtin_amdgcn_mfma_f32_32x32x16_bf16(afrag, bfr[nt], acc, 0, 0, 0);
            #pragma unroll
            for (int i = 0; i < 16; i++) {
                pA[nt] += acc[i];
                pB[nt] += __builtin_fabsf(acc[i]);
            }
        }
    }
    #pragma unroll
    for (int nt = 0; nt < 7; nt++) {
        pA[nt] += __shfl_xor(pA[nt], 32);
        pB[nt] += __shfl_xor(pB[nt], 32);
    }
    if (lane < 32) {
        #pragma unroll
        for (int nt = 0; nt < 7; nt++) {
            pool4A[wid][nt * 32 + lane] = pA[nt];
            pool4B[wid][nt * 32 + lane] = pB[nt];
        }
    }
    __syncthreads();

    if (t < NH) {
        float sa = pool4A[0][t] + pool4A[1][t] + pool4A[2][t] + pool4A[3][t];
        float sb = pool4B[0][t] + pool4B[1][t] + pool4B[2][t] + pool4B[3][t];
        pool_out[(size_t)r * NH + t] = (0.505f * sa + 0.495f * sb) * inv_nd;
    }
}

// ---------- head v2: 4 rows/block, register row-batching ----------
__global__ __launch_bounds__(256) void head_kernel(
    const float* __restrict__ pool, const float* __restrict__ W1,
    const float* __restrict__ b1,   const float* __restrict__ W2,
    const float* __restrict__ b2,   float* __restrict__ out)
{
    __shared__ __align__(16) float poolL[4][200];
    __shared__ __align__(16) float h1L[4][200];
    const int t = threadIdx.x;
    const int r0 = blockIdx.x * 4;

    if (t < NH) {
        #pragma unroll
        for (int rr = 0; rr < 4; rr++) poolL[rr][t] = pool[(size_t)(r0 + rr) * NH + t];
    }
    __syncthreads();

    // stage 1: h1[rr][t] — each thread owns channel t for all 4 rows
    if (t < NH) {
        float a0 = b1[t], a1 = b1[t], a2 = b1[t], a3 = b1[t];
        const float* wc = W1 + t;
        #pragma unroll 2
        for (int k = 0; k < NH; k += 4) {
            float w0 = wc[(size_t)(k + 0) * NH];
            float w1 = wc[(size_t)(k + 1) * NH];
            float w2 = wc[(size_t)(k + 2) * NH];
            float w3 = wc[(size_t)(k + 3) * NH];
            float4 p0 = *reinterpret_cast<const float4*>(&poolL[0][k]);
            float4 p1 = *reinterpret_cast<const float4*>(&poolL[1][k]);
            float4 p2 = *reinterpret_cast<const float4*>(&poolL[2][k]);
            float4 p3 = *reinterpret_cast<const float4*>(&poolL[3][k]);
            a0 += p0.x * w0 + p0.y * w1 + p0.z * w2 + p0.w * w3;
            a1 += p1.x * w0 + p1.y * w1 + p1.z * w2 + p1.w * w3;
            a2 += p2.x * w0 + p2.y * w1 + p2.z * w2 + p2.w * w3;
            a3 += p3.x * w0 + p3.y * w1 + p3.z * w2 + p3.w * w3;
        }
        h1L[0][t] = fmaxf(a0, 0.01f * a0);
        h1L[1][t] = fmaxf(a1, 0.01f * a1);
        h1L[2][t] = fmaxf(a2, 0.01f * a2);
        h1L[3][t] = fmaxf(a3, 0.01f * a3);
    }
    __syncthreads();

    // stage 2: out[rr][t] — each thread owns output t for all 4 rows
    if (t < KL) {
        float a0 = b2[t], a1 = b2[t], a2 = b2[t], a3 = b2[t];
        const float* wc = W2 + t;
        #pragma unroll 2
        for (int k = 0; k < NH; k += 4) {
            float w0 = wc[(size_t)(k + 0) * KL];
            float w1 = wc[(size_t)(k + 1) * KL];
            float w2 = wc[(size_t)(k + 2) * KL];
            float w3 = wc[(size_t)(k + 3) * KL];
            float4 p0 = *reinterpret_cast<const float4*>(&h1L[0][k]);
            float4 p1 = *reinterpret_cast<const float4*>(&h1L[1][k]);
            float4 p2 = *reinterpret_cast<const float4*>(&h1L[2][k]);
            float4 p3 = *reinterpret_cast<const float4*>(&h1L[3][k]);
            a0 += p0.x * w0 + p0.y * w1 + p0.z * w2 + p0.w * w3;
            a1 += p1.x * w0 + p1.y * w1 + p1.z * w2 + p1.w * w3;
            a2 += p2.x * w0 + p2.y * w1 + p2.z * w2 + p2.w * w3;
            a3 += p3.x * w0 + p3.y * w1 + p3.z * w2 + p3.w * w3;
        }
        out[(size_t)(r0 + 0) * KL + t] = a0;
        out[(size_t)(r0 + 1) * KL + t] = a1;
        out[(size_t)(r0 + 2) * KL + t] = a2;
        out[(size_t)(r0 + 3) * KL + t] = a3;
    }
}

extern "C" void kernel_launch(void* const* d_in, const int* in_sizes, int n_in,
                              void* d_out, int out_size, void* d_ws, size_t ws_size,
                              hipStream_t stream) {
    const float* x0    = (const float*)d_in[0];
    const float* x     = (const float*)d_in[1];
    const float* Nn    = (const float*)d_in[2];
    const float* basis = (const float*)d_in[3];
    const float* v     = (const float*)d_in[4];
    const float* W0    = (const float*)d_in[5];
    const float* b0    = (const float*)d_in[6];
    const float* W1    = (const float*)d_in[7];
    const float* b1    = (const float*)d_in[8];
    const float* W2    = (const float*)d_in[9];
    const float* b2    = (const float*)d_in[10];
    float* out = (float*)d_out;

    const int rows = in_sizes[2];       // B * NT = 2048
    float* pool_ws = (float*)d_ws;                                   // rows*196*4 = 1,605,632 B
    uint4* w0frag  = (uint4*)((char*)d_ws + (size_t)rows * NH * 4);  // +7,168 B (16B-aligned)

    prep_kernel<<<dim3(1), dim3(448), 0, stream>>>(W0, w0frag);
    pool_kernel<<<dim3(rows), dim3(256), 0, stream>>>(
        x0, x, Nn, basis, v, W0, b0, w0frag, pool_ws);
    head_kernel<<<dim3(rows / 4), dim3(256), 0, stream>>>(
        pool_ws, W1, b1, W2, b2, out);
}

// Round 16
// 129.456 us; speedup vs baseline: 1.8708x; 1.1692x over previous
//
#include <hip/hip_runtime.h>

typedef __bf16 bf16x8 __attribute__((ext_vector_type(8)));
typedef float f32x16 __attribute__((ext_vector_type(16)));

constexpr int NT = 1024;
constexpr int ND = 512;
constexpr int NB = 6;
constexpr int NH = 196;
constexpr int KL = 128;
constexpr int NHP = 224;   // 7 * 32 padded channels
constexpr int KP = 208;    // 13 * 16 padded K for head GEMMs

// ws layout (bytes) — total 1,005,568 B, well under the proven-safe 1.61 MB
constexpr size_t W0F_OFF = 0;         // 448*16  =   7,168
constexpr size_t W1F_OFF = 7168;      // 5824*16 =  93,184
constexpr size_t W2F_OFF = 100352;    // 3328*16 =  53,248
constexpr size_t H1B_OFF = 153600;    // 2048*208*2 = 851,968 -> ends 1,005,568
// poolb (bf16 [2048][208] = 851,968 B) lives in d_out (2048*128*4 = 1,048,576 B):
// stream order pool->h1->h2 guarantees h2's fp32 stores overwrite it last.

__device__ __forceinline__ unsigned short f2bf(float f) {
    unsigned int b = __float_as_uint(f);
    b += 0x7FFFu + ((b >> 16) & 1u);
    return (unsigned short)(b >> 16);
}

// ---------- prep: pack W0/W1/W2 into MFMA B-fragments (bf16) ----------
// fragment: lane holds col=lane&31, k = ks*16 + 8*(lane>>5) + e
__global__ __launch_bounds__(256) void prep_kernel(
    const float* __restrict__ W0, const float* __restrict__ W1,
    const float* __restrict__ W2,
    uint4* __restrict__ w0f, uint4* __restrict__ w1f, uint4* __restrict__ w2f)
{
    const int tid = blockIdx.x * 256 + threadIdx.x;
    if (tid < 448) {
        // W0 per-j rows (15..28), single K-step of 16
        const int l = tid & 63, nt = tid >> 6;
        const int c = nt * 32 + (l & 31);
        const int khalf = l >> 5;
        unsigned int w[4];
        #pragma unroll
        for (int d = 0; d < 4; d++) {
            int k0 = khalf * 8 + 2 * d, k1 = k0 + 1;
            float v0 = (c < NH && k0 < 14) ? W0[(15 + k0) * NH + c] : 0.f;
            float v1 = (c < NH && k1 < 14) ? W0[(15 + k1) * NH + c] : 0.f;
            w[d] = (unsigned int)f2bf(v0) | ((unsigned int)f2bf(v1) << 16);
        }
        w0f[tid] = make_uint4(w[0], w[1], w[2], w[3]);
    } else if (tid < 448 + 7 * 13 * 64) {
        // W1 [196x196] -> 7 n-tiles x 13 k-steps
        const int i = tid - 448;
        const int l = i & 63, rest = i >> 6;
        const int ks = rest % 13, nt = rest / 13;
        const int c = nt * 32 + (l & 31);
        const int kb = ks * 16 + (l >> 5) * 8;
        unsigned int w[4];
        #pragma unroll
        for (int d = 0; d < 4; d++) {
            int k0 = kb + 2 * d, k1 = k0 + 1;
            float v0 = (c < NH && k0 < NH) ? W1[(size_t)k0 * NH + c] : 0.f;
            float v1 = (c < NH && k1 < NH) ? W1[(size_t)k1 * NH + c] : 0.f;
            w[d] = (unsigned int)f2bf(v0) | ((unsigned int)f2bf(v1) << 16);
        }
        w1f[i] = make_uint4(w[0], w[1], w[2], w[3]);
    } else if (tid < 448 + 7 * 13 * 64 + 4 * 13 * 64) {
        // W2 [196x128] -> 4 n-tiles x 13 k-steps
        const int i = tid - 448 - 7 * 13 * 64;
        const int l = i & 63, rest = i >> 6;
        const int ks = rest % 13, nt = rest / 13;
        const int c = nt * 32 + (l & 31);
        const int kb = ks * 16 + (l >> 5) * 8;
        unsigned int w[4];
        #pragma unroll
        for (int d = 0; d < 4; d++) {
            int k0 = kb + 2 * d, k1 = k0 + 1;
            float v0 = (k0 < NH) ? W2[(size_t)k0 * KL + c] : 0.f;
            float v1 = (k1 < NH) ? W2[(size_t)k1 * KL + c] : 0.f;
            w[d] = (unsigned int)f2bf(v0) | ((unsigned int)f2bf(v1) << 16);
        }
        w2f[i] = make_uint4(w[0], w[1], w[2], w[3]);
    }
}

// ---------- pool: features + layer0 MFMA + lrelu-pool; writes bf16 [2048][208] ----------
__global__ __launch_bounds__(256) void pool_kernel(
    const float* __restrict__ x0, const float* __restrict__ x,
    const float* __restrict__ Nn, const float* __restrict__ basis,
    const float* __restrict__ v,  const float* __restrict__ W0,
    const float* __restrict__ b0, const uint4* __restrict__ w0frag,
    unsigned short* __restrict__ pool_out)
{
    __shared__ __align__(16) unsigned short featB[ND][16];
    __shared__ float consthL[NHP];
    __shared__ float pool4A[4][NHP];
    __shared__ float pool4B[4][NHP];
    __shared__ float red[4][3];

    const int r = blockIdx.x;
    const int t = threadIdx.x;
    const int wid = t >> 6;
    const int lane = t & 63;
    const int b = r >> 10;
    const size_t rowbase = (size_t)r * ND * 3;

    // ---- vbulk = mean_j v ----
    float s0 = 0.f, s1 = 0.f, s2 = 0.f;
    for (int j = t; j < ND; j += 256) {
        const float* vp = v + rowbase + 3 * j;
        s0 += vp[0]; s1 += vp[1]; s2 += vp[2];
    }
    #pragma unroll
    for (int off = 32; off > 0; off >>= 1) {
        s0 += __shfl_down(s0, off);
        s1 += __shfl_down(s1, off);
        s2 += __shfl_down(s2, off);
    }
    if (lane == 0) { red[wid][0] = s0; red[wid][1] = s1; red[wid][2] = s2; }
    __syncthreads();
    const float inv_nd = 1.0f / (float)ND;
    const float vb0 = (red[0][0] + red[1][0] + red[2][0] + red[3][0]) * inv_nd;
    const float vb1 = (red[0][1] + red[1][1] + red[2][1] + red[3][1]) * inv_nd;
    const float vb2 = (red[0][2] + red[1][2] + red[2][2] + red[3][2]) * inv_nd;

    float bx[NB], by[NB], bz[NB];
    {
        const float* bp = basis + (size_t)b * NB * 3;
        #pragma unroll
        for (int k = 0; k < NB; k++) { bx[k] = bp[3*k]; by[k] = bp[3*k+1]; bz[k] = bp[3*k+2]; }
    }

    // ---- per-j features -> LDS (bf16) ----
    for (int j = t; j < ND; j += 256) {
        const float* xp = x + rowbase + 3 * j;
        const float* vp = v + rowbase + 3 * j;
        float xa = xp[0], xbv = xp[1], xc = xp[2];
        float va = vp[0] - vb0, vbv = vp[1] - vb1, vcv = vp[2] - vb2;
        float n2x = xa*xa + xbv*xbv + xc*xc;
        float n2v = va*va + vbv*vbv + vcv*vcv;
        float rx = __frsqrt_rn(n2x);
        float rv = __frsqrt_rn(n2v);
        float f[14];
        f[0] = n2x * rx;
        #pragma unroll
        for (int k = 0; k < NB; k++) f[1+k] = (xa*bx[k] + xbv*by[k] + xc*bz[k]) * rx;
        f[7] = n2v * rv;
        #pragma unroll
        for (int k = 0; k < NB; k++) f[8+k] = (va*bx[k] + vbv*by[k] + vcv*bz[k]) * rv;
        bf16x8 lo, hi;
        #pragma unroll
        for (int e = 0; e < 8; e++) lo[e] = (__bf16)f[e];
        #pragma unroll
        for (int e = 0; e < 6; e++) hi[e] = (__bf16)f[8+e];
        hi[6] = (__bf16)0.f; hi[7] = (__bf16)0.f;
        *reinterpret_cast<uint4*>(&featB[j][0]) = __builtin_bit_cast(uint4, lo);
        *reinterpret_cast<uint4*>(&featB[j][8]) = __builtin_bit_cast(uint4, hi);
    }

    bf16x8 bfr[7];
    #pragma unroll
    for (int nt = 0; nt < 7; nt++)
        bfr[nt] = __builtin_bit_cast(bf16x8, w0frag[nt * 64 + lane]);

    // ---- constant features (fp32, folded into acc init) ----
    float cf[15];
    {
        const float* xp = x0 + (size_t)r * 3;
        float a0 = xp[0], a1 = xp[1], a2 = xp[2];
        float n20 = a0*a0 + a1*a1 + a2*a2;
        float n2b = vb0*vb0 + vb1*vb1 + vb2*vb2;
        float r0 = __frsqrt_rn(n20);
        float r1 = __frsqrt_rn(n2b);
        cf[0] = Nn[r];
        cf[1] = n20 * r0;
        #pragma unroll
        for (int k = 0; k < NB; k++) cf[2+k] = (a0*bx[k] + a1*by[k] + a2*bz[k]) * r0;
        cf[8] = n2b * r1;
        #pragma unroll
        for (int k = 0; k < NB; k++) cf[9+k] = (vb0*bx[k] + vb1*by[k] + vb2*bz[k]) * r1;
    }
    if (t < NHP) {
        float ch = 0.f;
        if (t < NH) {
            ch = b0[t];
            #pragma unroll
            for (int f2 = 0; f2 < 15; f2++) ch += cf[f2] * W0[f2 * NH + t];
        }
        consthL[t] = ch;
    }
    __syncthreads();

    const int col = lane & 31;
    const int khalf = lane >> 5;
    float ch[7];
    #pragma unroll
    for (int nt = 0; nt < 7; nt++) ch[nt] = consthL[nt * 32 + col];

    // ---- MFMA + A/B pooling: lrelu(h) = 0.505h + 0.495|h| ----
    float pA[7] = {0.f,0.f,0.f,0.f,0.f,0.f,0.f};
    float pB[7] = {0.f,0.f,0.f,0.f,0.f,0.f,0.f};
    #pragma unroll
    for (int mi = 0; mi < 4; mi++) {
        const int row = (wid * 4 + mi) * 32 + col;
        uint4 araw = *reinterpret_cast<const uint4*>(&featB[row][khalf * 8]);
        bf16x8 afrag = __builtin_bit_cast(bf16x8, araw);
        #pragma unroll
        for (int nt = 0; nt < 7; nt++) {
            f32x16 acc;
            #pragma unroll
            for (int i = 0; i < 16; i++) acc[i] = ch[nt];
            acc = __builtin_amdgcn_mfma_f32_32x32x16_bf16(afrag, bfr[nt], acc, 0, 0, 0);
            #pragma unroll
            for (int i = 0; i < 16; i++) {
                pA[nt] += acc[i];
                pB[nt] += __builtin_fabsf(acc[i]);
            }
        }
    }
    #pragma unroll
    for (int nt = 0; nt < 7; nt++) {
        pA[nt] += __shfl_xor(pA[nt], 32);
        pB[nt] += __shfl_xor(pB[nt], 32);
    }
    if (lane < 32) {
        #pragma unroll
        for (int nt = 0; nt < 7; nt++) {
            pool4A[wid][nt * 32 + lane] = pA[nt];
            pool4B[wid][nt * 32 + lane] = pB[nt];
        }
    }
    __syncthreads();

    if (t < KP) {
        float val = 0.f;
        if (t < NH) {
            float sa = pool4A[0][t] + pool4A[1][t] + pool4A[2][t] + pool4A[3][t];
            float sb = pool4B[0][t] + pool4B[1][t] + pool4B[2][t] + pool4B[3][t];
            val = (0.505f * sa + 0.495f * sb) * inv_nd;
        }
        pool_out[(size_t)r * KP + t] = f2bf(val);   // bf16, zero-padded to 208
    }
}

// ---------- H1: h1[2048x208] = lrelu(pool @ W1 + b1), bf16 out ----------
__global__ __launch_bounds__(64) void h1_kernel(
    const unsigned short* __restrict__ poolb, const uint4* __restrict__ w1f,
    const float* __restrict__ b1, unsigned short* __restrict__ h1b)
{
    const int rt = blockIdx.x / 7, nt = blockIdx.x % 7;
    const int lane = threadIdx.x;
    const int col = lane & 31, half = lane >> 5;
    const int col_g = nt * 32 + col;

    float binit = (col_g < NH) ? b1[col_g] : 0.f;
    f32x16 acc;
    #pragma unroll
    for (int i = 0; i < 16; i++) acc[i] = binit;

    const unsigned short* abase = poolb + (size_t)(rt * 32 + (lane & 31)) * KP + half * 8;
    #pragma unroll
    for (int ks = 0; ks < 13; ks++) {
        uint4 a = *reinterpret_cast<const uint4*>(abase + ks * 16);
        uint4 bq = w1f[(nt * 13 + ks) * 64 + lane];
        acc = __builtin_amdgcn_mfma_f32_32x32x16_bf16(
            __builtin_bit_cast(bf16x8, a), __builtin_bit_cast(bf16x8, bq), acc, 0, 0, 0);
    }

    if (col_g < KP) {
        #pragma unroll
        for (int i = 0; i < 16; i++) {
            int row = (i & 3) + 8 * (i >> 2) + 4 * half;
            float h = acc[i];
            h = fmaxf(h, 0.01f * h);
            h1b[(size_t)(rt * 32 + row) * KP + col_g] = f2bf(h);
        }
    }
}

// ---------- H2: out[2048x128] = h1 @ W2 + b2, fp32 out ----------
__global__ __launch_bounds__(64) void h2_kernel(
    const unsigned short* __restrict__ h1b, const uint4* __restrict__ w2f,
    const float* __restrict__ b2, float* __restrict__ out)
{
    const int rt = blockIdx.x / 4, nt = blockIdx.x % 4;
    const int lane = threadIdx.x;
    const int col = lane & 31, half = lane >> 5;
    const int col_g = nt * 32 + col;

    float binit = b2[col_g];
    f32x16 acc;
    #pragma unroll
    for (int i = 0; i < 16; i++) acc[i] = binit;

    const unsigned short* abase = h1b + (size_t)(rt * 32 + (lane & 31)) * KP + half * 8;
    #pragma unroll
    for (int ks = 0; ks < 13; ks++) {
        uint4 a = *reinterpret_cast<const uint4*>(abase + ks * 16);
        uint4 bq = w2f[(nt * 13 + ks) * 64 + lane];
        acc = __builtin_amdgcn_mfma_f32_32x32x16_bf16(
            __builtin_bit_cast(bf16x8, a), __builtin_bit_cast(bf16x8, bq), acc, 0, 0, 0);
    }

    #pragma unroll
    for (int i = 0; i < 16; i++) {
        int row = (i & 3) + 8 * (i >> 2) + 4 * half;
        out[(size_t)(rt * 32 + row) * KL + col_g] = acc[i];
    }
}

extern "C" void kernel_launch(void* const* d_in, const int* in_sizes, int n_in,
                              void* d_out, int out_size, void* d_ws, size_t ws_size,
                              hipStream_t stream) {
    const float* x0    = (const float*)d_in[0];
    const float* x     = (const float*)d_in[1];
    const float* Nn    = (const float*)d_in[2];
    const float* basis = (const float*)d_in[3];
    const float* v     = (const float*)d_in[4];
    const float* W0    = (const float*)d_in[5];
    const float* b0    = (const float*)d_in[6];
    const float* W1    = (const float*)d_in[7];
    const float* b1    = (const float*)d_in[8];
    const float* W2    = (const float*)d_in[9];
    const float* b2    = (const float*)d_in[10];
    float* out = (float*)d_out;

    char* ws = (char*)d_ws;
    uint4* w0f = (uint4*)(ws + W0F_OFF);
    uint4* w1f = (uint4*)(ws + W1F_OFF);
    uint4* w2f = (uint4*)(ws + W2F_OFF);
    unsigned short* h1b = (unsigned short*)(ws + H1B_OFF);
    // poolb lives in d_out (852 KB needed, 1 MB available); h2 overwrites it last.
    unsigned short* poolb = (unsigned short*)d_out;

    const int rows = in_sizes[2];       // B * NT = 2048
    const int prep_threads = 448 + 7 * 13 * 64 + 4 * 13 * 64;   // 9600
    prep_kernel<<<dim3((prep_threads + 255) / 256), dim3(256), 0, stream>>>(
        W0, W1, W2, w0f, w1f, w2f);
    pool_kernel<<<dim3(rows), dim3(256), 0, stream>>>(
        x0, x, Nn, basis, v, W0, b0, w0f, poolb);
    h1_kernel<<<dim3((rows / 32) * 7), dim3(64), 0, stream>>>(poolb, w1f, b1, h1b);
    h2_kernel<<<dim3((rows / 32) * 4), dim3(64), 0, stream>>>(h1b, w2f, b2, out);
}